// Round 9
// baseline (361.331 us; speedup 1.0000x reference)
//
#include <hip/hip_runtime.h>
#include <stdint.h>

typedef unsigned short ushort_t;
typedef __attribute__((ext_vector_type(8))) short bf16x8;
typedef __attribute__((ext_vector_type(4))) float f32x4;
typedef __attribute__((ext_vector_type(4))) unsigned short us4;

#define DEV __device__ __forceinline__

DEV ushort_t f2bf(float f) {
    unsigned int u = __float_as_uint(f);
    u += 0x7fffu + ((u >> 16) & 1u);
    return (ushort_t)(u >> 16);
}

DEV void async16(const ushort_t* g, ushort_t* l) {
    __builtin_amdgcn_global_load_lds(
        (const __attribute__((address_space(1))) void*)g,
        (__attribute__((address_space(3))) void*)l,
        16, 0, 0);
}

// ---------------------------------------------------------------------------
// f32 -> bf16 conversion of x and the four weight matrices (one launch).
// ---------------------------------------------------------------------------
__global__ void convert_kernel(const float* __restrict__ x, const float* __restrict__ wq,
                               const float* __restrict__ wk, const float* __restrict__ wv,
                               const float* __restrict__ wo,
                               ushort_t* __restrict__ xb, ushort_t* __restrict__ wqb,
                               ushort_t* __restrict__ wkb, ushort_t* __restrict__ wvb,
                               ushort_t* __restrict__ wob)
{
    const int i = blockIdx.x * 256 + threadIdx.x; // float4 index, 1048576 total
    const float* src; ushort_t* dst; int off;
    if (i < 524288)      { src = x;  dst = xb;  off = i; }
    else if (i < 655360) { src = wq; dst = wqb; off = i - 524288; }
    else if (i < 786432) { src = wk; dst = wkb; off = i - 655360; }
    else if (i < 917504) { src = wv; dst = wvb; off = i - 786432; }
    else                 { src = wo; dst = wob; off = i - 917504; }
    const float4 v = ((const float4*)src)[off];
    us4 o;
    o[0] = f2bf(v.x); o[1] = f2bf(v.y); o[2] = f2bf(v.z); o[3] = f2bf(v.w);
    ((us4*)dst)[off] = o;
}

// ---------------------------------------------------------------------------
// Merged Q/K/V projection GEMM: z = blockIdx.z selects weight + output.
// C[M][N] = A[M][K] * B[N][K]^T, M=8192, N=2048, K=256.
// z=0 -> q_out SCALED by 1/16 (exact bf16 exponent shift), z=1 -> k_out,
// z=2 -> vt_out ([b][h][d][l]).
// ---------------------------------------------------------------------------
__global__ __launch_bounds__(256, 2) void qkv_gemm_kernel(
    const ushort_t* __restrict__ A, const ushort_t* __restrict__ wq,
    const ushort_t* __restrict__ wk, const ushort_t* __restrict__ wv,
    ushort_t* __restrict__ q_out, ushort_t* __restrict__ k_out,
    ushort_t* __restrict__ vt_out)
{
    __shared__ ushort_t At[128 * 64];
    __shared__ ushort_t Bt[128 * 64];

    const int K = 256, N = 2048;
    const int z = blockIdx.z;
    const ushort_t* Bm = (z == 0) ? wq : (z == 1) ? wk : wv;

    const int tid  = threadIdx.x;
    const int wave = tid >> 6;
    const int lane = tid & 63;
    const int quad = lane >> 4;
    const int l15  = lane & 15;
    const int mhalf = wave >> 1;
    const int nhalf = wave & 1;
    const int m0 = blockIdx.x * 128;
    const int n0 = blockIdx.y * 128;

    f32x4 acc[4][4];
#pragma unroll
    for (int mf = 0; mf < 4; ++mf)
#pragma unroll
        for (int nf = 0; nf < 4; ++nf)
#pragma unroll
            for (int r = 0; r < 4; ++r) acc[mf][nf][r] = 0.f;

    const int crow = (lane & 7) ^ (lane >> 3);

    for (int k0 = 0; k0 < K; k0 += 64) {
        __syncthreads();
#pragma unroll
        for (int t = 0; t < 4; ++t) {
            const int row = wave * 32 + t * 8 + (lane >> 3);
            async16(A + (size_t)(m0 + row) * K + k0 + crow * 8,
                    At + (wave * 32 + t * 8) * 64 + lane * 8);
            async16(Bm + (size_t)(n0 + row) * K + k0 + crow * 8,
                    Bt + (wave * 32 + t * 8) * 64 + lane * 8);
        }
        __syncthreads();
#pragma unroll
        for (int ks = 0; ks < 2; ++ks) {
            bf16x8 af[4], bf[4];
#pragma unroll
            for (int mf = 0; mf < 4; ++mf) {
                const int ml = mhalf * 64 + mf * 16 + l15;
                const int c = (ks * 4 + quad) ^ (ml & 7);
                af[mf] = *(const bf16x8*)(At + ml * 64 + c * 8);
            }
#pragma unroll
            for (int nf = 0; nf < 4; ++nf) {
                const int nl = nhalf * 64 + nf * 16 + l15;
                const int c = (ks * 4 + quad) ^ (nl & 7);
                bf[nf] = *(const bf16x8*)(Bt + nl * 64 + c * 8);
            }
#pragma unroll
            for (int mf = 0; mf < 4; ++mf)
#pragma unroll
                for (int nf = 0; nf < 4; ++nf)
                    acc[mf][nf] = __builtin_amdgcn_mfma_f32_16x16x32_bf16(
                        af[mf], bf[nf], acc[mf][nf], 0, 0, 0);
        }
    }

    if (z == 2) {
#pragma unroll
        for (int mf = 0; mf < 4; ++mf)
#pragma unroll
            for (int nf = 0; nf < 4; ++nf) {
                const int row = m0 + mhalf * 64 + mf * 16 + quad * 4;
                const int col = n0 + nhalf * 64 + nf * 16 + l15;
                const int b_ = row >> 11, l_ = row & 2047;
                const int h_ = col >> 8, d_ = col & 255;
                us4 pk;
#pragma unroll
                for (int r = 0; r < 4; ++r) pk[r] = f2bf(acc[mf][nf][r]);
                *(us4*)(vt_out + (((size_t)(b_ * 8 + h_) * 256 + d_) * 2048 + l_)) = pk;
            }
    } else {
        ushort_t* Cout = z ? k_out : q_out;
        const float sc = z ? 1.0f : 0.0625f;   // fold 1/sqrt(256) into Q (exact)
#pragma unroll
        for (int mf = 0; mf < 4; ++mf)
#pragma unroll
            for (int nf = 0; nf < 4; ++nf)
#pragma unroll
                for (int r = 0; r < 4; ++r) {
                    const int row = m0 + mhalf * 64 + mf * 16 + quad * 4 + r;
                    const int col = n0 + nhalf * 64 + nf * 16 + l15;
                    Cout[(size_t)row * N + col] = f2bf(acc[mf][nf][r] * sc);
                }
    }
}

// ---------------------------------------------------------------------------
// Output GEMM, split-K: C_partial[s][M][N] = A[M][Ks] * B[N][Ks]^T.
// ---------------------------------------------------------------------------
__global__ __launch_bounds__(256, 2) void out_gemm_splitk_kernel(
    const ushort_t* __restrict__ A, const ushort_t* __restrict__ Bm,
    float* __restrict__ Pout, int M, int N, int K)
{
    __shared__ ushort_t At[128 * 64];
    __shared__ ushort_t Bt[128 * 64];

    const int tid  = threadIdx.x;
    const int wave = tid >> 6;
    const int lane = tid & 63;
    const int quad = lane >> 4;
    const int l15  = lane & 15;
    const int mhalf = wave >> 1;
    const int nhalf = wave & 1;
    const int m0 = blockIdx.x * 128;
    const int n0 = blockIdx.y * 128;
    const int ks0 = blockIdx.z * 512;

    f32x4 acc[4][4];
#pragma unroll
    for (int mf = 0; mf < 4; ++mf)
#pragma unroll
        for (int nf = 0; nf < 4; ++nf)
#pragma unroll
            for (int r = 0; r < 4; ++r) acc[mf][nf][r] = 0.f;

    const int crow = (lane & 7) ^ (lane >> 3);

    for (int k0 = ks0; k0 < ks0 + 512; k0 += 64) {
        __syncthreads();
#pragma unroll
        for (int t = 0; t < 4; ++t) {
            const int row = wave * 32 + t * 8 + (lane >> 3);
            async16(A + (size_t)(m0 + row) * K + k0 + crow * 8,
                    At + (wave * 32 + t * 8) * 64 + lane * 8);
            async16(Bm + (size_t)(n0 + row) * K + k0 + crow * 8,
                    Bt + (wave * 32 + t * 8) * 64 + lane * 8);
        }
        __syncthreads();
#pragma unroll
        for (int ks = 0; ks < 2; ++ks) {
            bf16x8 af[4], bf[4];
#pragma unroll
            for (int mf = 0; mf < 4; ++mf) {
                const int ml = mhalf * 64 + mf * 16 + l15;
                const int c = (ks * 4 + quad) ^ (ml & 7);
                af[mf] = *(const bf16x8*)(At + ml * 64 + c * 8);
            }
#pragma unroll
            for (int nf = 0; nf < 4; ++nf) {
                const int nl = nhalf * 64 + nf * 16 + l15;
                const int c = (ks * 4 + quad) ^ (nl & 7);
                bf[nf] = *(const bf16x8*)(Bt + nl * 64 + c * 8);
            }
#pragma unroll
            for (int mf = 0; mf < 4; ++mf)
#pragma unroll
                for (int nf = 0; nf < 4; ++nf)
                    acc[mf][nf] = __builtin_amdgcn_mfma_f32_16x16x32_bf16(
                        af[mf], bf[nf], acc[mf][nf], 0, 0, 0);
        }
    }

    float* Cp = Pout + (size_t)blockIdx.z * M * N;
#pragma unroll
    for (int mf = 0; mf < 4; ++mf)
#pragma unroll
        for (int nf = 0; nf < 4; ++nf)
#pragma unroll
            for (int r = 0; r < 4; ++r) {
                const int row = m0 + mhalf * 64 + mf * 16 + quad * 4 + r;
                const int col = n0 + nhalf * 64 + nf * 16 + l15;
                Cp[(size_t)row * N + col] = acc[mf][nf][r];
            }
}

// sum the 4 split-K partials -> d_out. 524288 float4 elements.
__global__ void reduce4_kernel(const float4* __restrict__ p, float4* __restrict__ out)
{
    const int i = blockIdx.x * 256 + threadIdx.x;
    float4 a = p[i];
    const float4 b = p[i + 524288];
    const float4 c = p[i + 1048576];
    const float4 d = p[i + 1572864];
    a.x += b.x + c.x + d.x;
    a.y += b.y + c.y + d.y;
    a.z += b.z + c.z + d.z;
    a.w += b.w + c.w + d.w;
    out[i] = a;
}

// ---------------------------------------------------------------------------
// Unsplit output GEMM (fallback if workspace can't hold partials).
// ---------------------------------------------------------------------------
__global__ __launch_bounds__(256, 2) void out_gemm_kernel(
    const ushort_t* __restrict__ A, const ushort_t* __restrict__ Bm,
    float* __restrict__ Cout, int M, int N, int K)
{
    __shared__ ushort_t At[128 * 64];
    __shared__ ushort_t Bt[128 * 64];

    const int tid  = threadIdx.x;
    const int wave = tid >> 6;
    const int lane = tid & 63;
    const int quad = lane >> 4;
    const int l15  = lane & 15;
    const int mhalf = wave >> 1;
    const int nhalf = wave & 1;
    const int m0 = blockIdx.x * 128;
    const int n0 = blockIdx.y * 128;

    f32x4 acc[4][4];
#pragma unroll
    for (int mf = 0; mf < 4; ++mf)
#pragma unroll
        for (int nf = 0; nf < 4; ++nf)
#pragma unroll
            for (int r = 0; r < 4; ++r) acc[mf][nf][r] = 0.f;

    const int crow = (lane & 7) ^ (lane >> 3);

    for (int k0 = 0; k0 < K; k0 += 64) {
        __syncthreads();
#pragma unroll
        for (int t = 0; t < 4; ++t) {
            const int row = wave * 32 + t * 8 + (lane >> 3);
            async16(A + (size_t)(m0 + row) * K + k0 + crow * 8,
                    At + (wave * 32 + t * 8) * 64 + lane * 8);
            async16(Bm + (size_t)(n0 + row) * K + k0 + crow * 8,
                    Bt + (wave * 32 + t * 8) * 64 + lane * 8);
        }
        __syncthreads();
#pragma unroll
        for (int ks = 0; ks < 2; ++ks) {
            bf16x8 af[4], bf[4];
#pragma unroll
            for (int mf = 0; mf < 4; ++mf) {
                const int ml = mhalf * 64 + mf * 16 + l15;
                const int c = (ks * 4 + quad) ^ (ml & 7);
                af[mf] = *(const bf16x8*)(At + ml * 64 + c * 8);
            }
#pragma unroll
            for (int nf = 0; nf < 4; ++nf) {
                const int nl = nhalf * 64 + nf * 16 + l15;
                const int c = (ks * 4 + quad) ^ (nl & 7);
                bf[nf] = *(const bf16x8*)(Bt + nl * 64 + c * 8);
            }
#pragma unroll
            for (int mf = 0; mf < 4; ++mf)
#pragma unroll
                for (int nf = 0; nf < 4; ++nf)
                    acc[mf][nf] = __builtin_amdgcn_mfma_f32_16x16x32_bf16(
                        af[mf], bf[nf], acc[mf][nf], 0, 0, 0);
        }
    }

#pragma unroll
    for (int mf = 0; mf < 4; ++mf)
#pragma unroll
        for (int nf = 0; nf < 4; ++nf)
#pragma unroll
            for (int r = 0; r < 4; ++r) {
                const int row = m0 + mhalf * 64 + mf * 16 + quad * 4 + r;
                const int col = n0 + nhalf * 64 + nf * 16 + l15;
                Cout[(size_t)row * N + col] = acc[mf][nf][r];
            }
}

// ---------------------------------------------------------------------------
// Pass 1: full-row softmax denominator Z_i = sum_j exp(s_ij) (s pre-scaled
// via Q). Grid 1024 = 32 bh x 32 i-tiles. LDS 32 KB -> 4 blocks/CU.
// T5 setprio KEPT here: 4 independent blocks/CU at different phases ->
// scheduler favors the MFMA-phase block (round-8 A/B: pass1 gained ~12 us).
// ---------------------------------------------------------------------------
__global__ __launch_bounds__(256, 4) void pass1_kernel(
    const ushort_t* __restrict__ q_ws, const ushort_t* __restrict__ k_ws,
    float* __restrict__ rz_ws)
{
    __shared__ ushort_t Kt[64 * 256];   // 32 KB, chunk-swizzled
    __shared__ float zred[2][64];

    const int tid  = threadIdx.x;
    const int wave = tid >> 6;
    const int lane = tid & 63;
    const int quad = lane >> 4;
    const int l15  = lane & 15;
    const int ihalf = wave >> 1;
    const int jhalf = wave & 1;

    const int g  = blockIdx.x;
    const int bh = ((g >> 8) << 3) | (g & 7);
    const int it = (g >> 3) & 31;
    const int b = bh >> 3, h = bh & 7;
    const int i0 = it * 64;

    const size_t qkbase = (size_t)b * 2048 * 2048 + (size_t)h * 256;

    // Q fragments (B-operand layout: n=l15 -> row i, k=quad*8.. -> d)
    bf16x8 qf[2][8];
#pragma unroll
    for (int ng = 0; ng < 2; ++ng) {
        const int i_l = ihalf * 32 + ng * 16 + l15;
        const ushort_t* qr = q_ws + qkbase + (size_t)(i0 + i_l) * 2048;
#pragma unroll
        for (int ks = 0; ks < 8; ++ks)
            qf[ng][ks] = *(const bf16x8*)(qr + ks * 32 + quad * 8);
    }

    float z[2] = {0.f, 0.f};

    for (int jt = 0; jt < 32; ++jt) {
        const int j0 = jt * 64;
        __syncthreads();
        {
            const ushort_t* kb = k_ws + qkbase + (size_t)j0 * 2048;
#pragma unroll
            for (int t = 0; t < 8; ++t) {
                const int row = wave * 16 + t * 2 + (lane >> 5);
                const int c = (lane & 31) ^ (row & 7);
                async16(kb + (size_t)row * 2048 + c * 8,
                        Kt + (wave * 16 + t * 2) * 256 + lane * 8);
            }
        }
        __syncthreads();

        f32x4 sacc[2][2];
#pragma unroll
        for (int a = 0; a < 2; ++a)
#pragma unroll
            for (int c = 0; c < 2; ++c)
#pragma unroll
                for (int r = 0; r < 4; ++r) sacc[a][c][r] = 0.f;

        __builtin_amdgcn_s_setprio(1);
#pragma unroll
        for (int ks = 0; ks < 8; ++ks) {
            bf16x8 af[2];
#pragma unroll
            for (int mg = 0; mg < 2; ++mg) {
                const int j_l = jhalf * 32 + mg * 16 + l15;
                const int c = (ks * 4 + quad) ^ (j_l & 7);
                af[mg] = *(const bf16x8*)(Kt + j_l * 256 + c * 8);
            }
#pragma unroll
            for (int mg = 0; mg < 2; ++mg)
#pragma unroll
                for (int ng = 0; ng < 2; ++ng)
                    sacc[mg][ng] = __builtin_amdgcn_mfma_f32_16x16x32_bf16(
                        af[mg], qf[ng][ks], sacc[mg][ng], 0, 0, 0);
        }
        __builtin_amdgcn_s_setprio(0);

#pragma unroll
        for (int ng = 0; ng < 2; ++ng)
#pragma unroll
            for (int mg = 0; mg < 2; ++mg)
#pragma unroll
                for (int r = 0; r < 4; ++r)
                    z[ng] += __expf(sacc[mg][ng][r]);
    }

    // reduce z across quads (same jhalf), then across jhalf via LDS
#pragma unroll
    for (int ng = 0; ng < 2; ++ng) {
        z[ng] += __shfl_xor(z[ng], 16);
        z[ng] += __shfl_xor(z[ng], 32);
    }
    __syncthreads();
    if (quad == 0) {
#pragma unroll
        for (int ng = 0; ng < 2; ++ng) {
            const int i_l = ihalf * 32 + ng * 16 + l15;
            zred[jhalf][i_l] = z[ng];
        }
    }
    __syncthreads();
    if (tid < 64)
        rz_ws[(size_t)bh * 2048 + i0 + tid] = 1.0f / (zred[0][tid] + zred[1][tid]);
}

// ---------------------------------------------------------------------------
// Pass 2: causal w = exp(p), p = exp(s)/Z; PV accumulate; divide by sum(w).
// Grid 1024, it DESCENDING (heavy first). Round-0 proven core, NO setprio
// (round-8 A/B: setprio cost pass2 ~9 us — 2 blocks/CU lockstep regime).
// ---------------------------------------------------------------------------
__global__ __launch_bounds__(256, 2) void pass2_kernel(
    const ushort_t* __restrict__ q_ws, const ushort_t* __restrict__ k_ws,
    const ushort_t* __restrict__ vt_ws, const float* __restrict__ rz_ws,
    ushort_t* __restrict__ attn_out)
{
    __shared__ ushort_t smem[36864];          // 72 KB
    ushort_t* Kt = smem;                      // [64][256] swizzled (32 KB)
    ushort_t* Vt = smem + 16384;              // [256][64] swizzled (32 KB)
    ushort_t* Wt = smem + 32768;              // [64][64] swizzled (8 KB)

    const int tid  = threadIdx.x;
    const int wave = tid >> 6;
    const int lane = tid & 63;
    const int quad = lane >> 4;
    const int l15  = lane & 15;
    const int ihalf = wave >> 1;
    const int jhalf = wave & 1;

    const int g  = blockIdx.x;
    const int bh = ((g >> 8) << 3) | (g & 7);
    const int it = 31 - ((g >> 3) & 31);      // heavy (large it) dispatched first
    const int b = bh >> 3, h = bh & 7;
    const int i0 = it * 64;

    const size_t qkbase = (size_t)b * 2048 * 2048 + (size_t)h * 256;

    bf16x8 qf[2][8];
#pragma unroll
    for (int ng = 0; ng < 2; ++ng) {
        const int i_l = ihalf * 32 + ng * 16 + l15;
        const ushort_t* qr = q_ws + qkbase + (size_t)(i0 + i_l) * 2048;
#pragma unroll
        for (int ks = 0; ks < 8; ++ks)
            qf[ng][ks] = *(const bf16x8*)(qr + ks * 32 + quad * 8);
    }

    float rzrow[2];
#pragma unroll
    for (int ng = 0; ng < 2; ++ng) {
        const int i_l = ihalf * 32 + ng * 16 + l15;
        rzrow[ng] = rz_ws[(size_t)bh * 2048 + i0 + i_l];
    }

    f32x4 oacc[2][8];
#pragma unroll
    for (int mg = 0; mg < 2; ++mg)
#pragma unroll
        for (int nf = 0; nf < 8; ++nf)
#pragma unroll
            for (int r = 0; r < 4; ++r) oacc[mg][nf][r] = 0.f;
    float den[2] = {0.f, 0.f};

    for (int jt = 0; jt <= it; ++jt) {
        const int j0 = jt * 64;
        const bool diag = (jt == it);
        __syncthreads();
        {
            const ushort_t* kb = k_ws + qkbase + (size_t)j0 * 2048;
#pragma unroll
            for (int t = 0; t < 8; ++t) {
                const int row = wave * 16 + t * 2 + (lane >> 5);
                const int c = (lane & 31) ^ (row & 7);
                async16(kb + (size_t)row * 2048 + c * 8,
                        Kt + (wave * 16 + t * 2) * 256 + lane * 8);
            }
            const ushort_t* vb = vt_ws + (size_t)bh * 256 * 2048 + j0;
#pragma unroll
            for (int t = 0; t < 8; ++t) {
                const int row = wave * 64 + t * 8 + (lane >> 3);
                const int c = (lane & 7) ^ (row & 7);
                async16(vb + (size_t)row * 2048 + c * 8,
                        Vt + (wave * 64 + t * 8) * 64 + lane * 8);
            }
        }
        __syncthreads();

        f32x4 sacc[2][2];
#pragma unroll
        for (int a = 0; a < 2; ++a)
#pragma unroll
            for (int c = 0; c < 2; ++c)
#pragma unroll
                for (int r = 0; r < 4; ++r) sacc[a][c][r] = 0.f;

#pragma unroll
        for (int ks = 0; ks < 8; ++ks) {
            bf16x8 af[2];
#pragma unroll
            for (int mg = 0; mg < 2; ++mg) {
                const int j_l = jhalf * 32 + mg * 16 + l15;
                const int c = (ks * 4 + quad) ^ (j_l & 7);
                af[mg] = *(const bf16x8*)(Kt + j_l * 256 + c * 8);
            }
#pragma unroll
            for (int mg = 0; mg < 2; ++mg)
#pragma unroll
                for (int ng = 0; ng < 2; ++ng)
                    sacc[mg][ng] = __builtin_amdgcn_mfma_f32_16x16x32_bf16(
                        af[mg], qf[ng][ks], sacc[mg][ng], 0, 0, 0);
        }

        // w = exp(exp(s)*rz), causal-masked on diag tile; pack -> Wt[i][j]
#pragma unroll
        for (int mg = 0; mg < 2; ++mg) {
#pragma unroll
            for (int ng = 0; ng < 2; ++ng) {
                const int i_l = ihalf * 32 + ng * 16 + l15;
                const int jb = jhalf * 32 + mg * 16 + quad * 4;
                us4 wp;
#pragma unroll
                for (int r = 0; r < 4; ++r) {
                    const float p = __expf(sacc[mg][ng][r]) * rzrow[ng];
                    float w = __expf(p);
                    if (diag && (jb + r > i_l)) w = 0.f;
                    den[ng] += w;
                    wp[r] = f2bf(w);
                }
                const int c = (jb >> 3) ^ (i_l & 7);
                *(us4*)(Wt + i_l * 64 + c * 8 + (jb & 7)) = wp;
            }
        }
        __syncthreads();

        // PV: oacc[32 i][128 d] += Wt x Vt
#pragma unroll
        for (int ks = 0; ks < 2; ++ks) {
            bf16x8 aw[2];
#pragma unroll
            for (int mg = 0; mg < 2; ++mg) {
                const int i_l = ihalf * 32 + mg * 16 + l15;
                const int c = (ks * 4 + quad) ^ (i_l & 7);
                aw[mg] = *(const bf16x8*)(Wt + i_l * 64 + c * 8);
            }
#pragma unroll
            for (int nf = 0; nf < 8; ++nf) {
                const int d = jhalf * 128 + nf * 16 + l15;
                const int c = (ks * 4 + quad) ^ (d & 7);
                const bf16x8 bv = *(const bf16x8*)(Vt + d * 64 + c * 8);
                oacc[0][nf] = __builtin_amdgcn_mfma_f32_16x16x32_bf16(aw[0], bv, oacc[0][nf], 0, 0, 0);
                oacc[1][nf] = __builtin_amdgcn_mfma_f32_16x16x32_bf16(aw[1], bv, oacc[1][nf], 0, 0, 0);
            }
        }
    }

    // epilogue: merge den across waves, scale rows, store (round-0 proven)
    __syncthreads();
    {
        float* dbuf = (float*)Kt; // [8][64]
#pragma unroll
        for (int ng = 0; ng < 2; ++ng) {
            const int i_l = ihalf * 32 + ng * 16 + l15;
            dbuf[(jhalf * 4 + quad) * 64 + i_l] = den[ng];
        }
    }
    __syncthreads();
    if (tid < 64) {
        const float* dbuf = (const float*)Kt;
        float s = 0.f;
#pragma unroll
        for (int p = 0; p < 8; ++p) s += dbuf[p * 64 + tid];
        ((float*)Kt)[512 + tid] = 1.0f / s;
    }
    __syncthreads();
    {
        const float* rden = (const float*)Kt + 512;
#pragma unroll
        for (int mg = 0; mg < 2; ++mg) {
#pragma unroll
            for (int r = 0; r < 4; ++r) {
                const int i_l = ihalf * 32 + mg * 16 + quad * 4 + r;
                const float rd = rden[i_l];
                ushort_t* orow = attn_out + qkbase + (size_t)(i0 + i_l) * 2048;
#pragma unroll
                for (int nf = 0; nf < 8; ++nf) {
                    const int d = jhalf * 128 + nf * 16 + l15;
                    orow[d] = f2bf(oacc[mg][nf][r] * rd);
                }
            }
        }
    }
}

// ---------------------------------------------------------------------------
extern "C" void kernel_launch(void* const* d_in, const int* in_sizes, int n_in,
                              void* d_out, int out_size, void* d_ws, size_t ws_size,
                              hipStream_t stream) {
    const float* x  = (const float*)d_in[0];
    const float* Wq = (const float*)d_in[1];
    const float* Wk = (const float*)d_in[2];
    const float* Wv = (const float*)d_in[3];
    const float* Wo = (const float*)d_in[4];

    char* ws = (char*)d_ws;
    ushort_t* xb    = (ushort_t*)(ws);
    ushort_t* wqb   = (ushort_t*)(ws + 4194304);
    ushort_t* wkb   = (ushort_t*)(ws + 5242880);
    ushort_t* wvb   = (ushort_t*)(ws + 6291456);
    ushort_t* wob   = (ushort_t*)(ws + 7340032);
    ushort_t* q_ws  = (ushort_t*)(ws + 8388608);
    ushort_t* k_ws  = (ushort_t*)(ws + 41943040);
    ushort_t* vt_ws = (ushort_t*)(ws + 75497472);
    ushort_t* ao_ws = (ushort_t*)(ws + 109051904);
    float*    rz_ws = (float*)   (ws + 142606336);   // 32*2048 floats, ends 142868480

    // split-K partials: 4 x 8192 x 256 f32 = 32 MB
    const size_t PG_OFF = 142868480ull;
    const size_t PG_END = PG_OFF + 33554432ull;      // 176,422,912
    const bool use_splitk = ws_size >= PG_END;
    float* pg_ws = (float*)(ws + PG_OFF);

    convert_kernel<<<4096, 256, 0, stream>>>(x, Wq, Wk, Wv, Wo, xb, wqb, wkb, wvb, wob);

    qkv_gemm_kernel<<<dim3(64, 16, 3), 256, 0, stream>>>(
        xb, wqb, wkb, wvb, q_ws, k_ws, vt_ws);

    pass1_kernel<<<1024, 256, 0, stream>>>(q_ws, k_ws, rz_ws);
    pass2_kernel<<<1024, 256, 0, stream>>>(q_ws, k_ws, vt_ws, rz_ws, ao_ws);

    if (use_splitk) {
        out_gemm_splitk_kernel<<<dim3(64, 2, 4), 256, 0, stream>>>(
            ao_ws, wob, pg_ws, 8192, 256, 2048);
        reduce4_kernel<<<2048, 256, 0, stream>>>(
            (const float4*)pg_ws, (float4*)d_out);
    } else {
        out_gemm_kernel<<<dim3(64, 2), 256, 0, stream>>>(
            ao_ws, wob, (float*)d_out, 8192, 256, 2048);
    }
}

// Round 10
// 298.449 us; speedup vs baseline: 1.2107x; 1.2107x over previous
//
#include <hip/hip_runtime.h>
#include <stdint.h>

typedef unsigned short ushort_t;
typedef __attribute__((ext_vector_type(8))) short bf16x8;
typedef __attribute__((ext_vector_type(4))) float f32x4;
typedef __attribute__((ext_vector_type(4))) unsigned short us4;

#define DEV __device__ __forceinline__

DEV ushort_t f2bf(float f) {
    unsigned int u = __float_as_uint(f);
    u += 0x7fffu + ((u >> 16) & 1u);
    return (ushort_t)(u >> 16);
}

DEV void async16(const ushort_t* g, ushort_t* l) {
    __builtin_amdgcn_global_load_lds(
        (const __attribute__((address_space(1))) void*)g,
        (__attribute__((address_space(3))) void*)l,
        16, 0, 0);
}

// ---------------------------------------------------------------------------
// f32 -> bf16 conversion of x and the four weight matrices (one launch).
// ---------------------------------------------------------------------------
__global__ void convert_kernel(const float* __restrict__ x, const float* __restrict__ wq,
                               const float* __restrict__ wk, const float* __restrict__ wv,
                               const float* __restrict__ wo,
                               ushort_t* __restrict__ xb, ushort_t* __restrict__ wqb,
                               ushort_t* __restrict__ wkb, ushort_t* __restrict__ wvb,
                               ushort_t* __restrict__ wob)
{
    const int i = blockIdx.x * 256 + threadIdx.x; // float4 index, 1048576 total
    const float* src; ushort_t* dst; int off;
    if (i < 524288)      { src = x;  dst = xb;  off = i; }
    else if (i < 655360) { src = wq; dst = wqb; off = i - 524288; }
    else if (i < 786432) { src = wk; dst = wkb; off = i - 655360; }
    else if (i < 917504) { src = wv; dst = wvb; off = i - 786432; }
    else                 { src = wo; dst = wob; off = i - 917504; }
    const float4 v = ((const float4*)src)[off];
    us4 o;
    o[0] = f2bf(v.x); o[1] = f2bf(v.y); o[2] = f2bf(v.z); o[3] = f2bf(v.w);
    ((us4*)dst)[off] = o;
}

// ---------------------------------------------------------------------------
// Merged Q/K/V projection GEMM: z = blockIdx.z selects weight + output.
// C[M][N] = A[M][K] * B[N][K]^T, M=8192, N=2048, K=256.
// z=0 -> q_out SCALED by 1/16 (exact bf16 exponent shift), z=1 -> k_out,
// z=2 -> vt_out ([b][h][d][l]).
// ---------------------------------------------------------------------------
__global__ __launch_bounds__(256, 2) void qkv_gemm_kernel(
    const ushort_t* __restrict__ A, const ushort_t* __restrict__ wq,
    const ushort_t* __restrict__ wk, const ushort_t* __restrict__ wv,
    ushort_t* __restrict__ q_out, ushort_t* __restrict__ k_out,
    ushort_t* __restrict__ vt_out)
{
    __shared__ ushort_t At[128 * 64];
    __shared__ ushort_t Bt[128 * 64];

    const int K = 256, N = 2048;
    const int z = blockIdx.z;
    const ushort_t* Bm = (z == 0) ? wq : (z == 1) ? wk : wv;

    const int tid  = threadIdx.x;
    const int wave = tid >> 6;
    const int lane = tid & 63;
    const int quad = lane >> 4;
    const int l15  = lane & 15;
    const int mhalf = wave >> 1;
    const int nhalf = wave & 1;
    const int m0 = blockIdx.x * 128;
    const int n0 = blockIdx.y * 128;

    f32x4 acc[4][4];
#pragma unroll
    for (int mf = 0; mf < 4; ++mf)
#pragma unroll
        for (int nf = 0; nf < 4; ++nf)
#pragma unroll
            for (int r = 0; r < 4; ++r) acc[mf][nf][r] = 0.f;

    const int crow = (lane & 7) ^ (lane >> 3);

    for (int k0 = 0; k0 < K; k0 += 64) {
        __syncthreads();
#pragma unroll
        for (int t = 0; t < 4; ++t) {
            const int row = wave * 32 + t * 8 + (lane >> 3);
            async16(A + (size_t)(m0 + row) * K + k0 + crow * 8,
                    At + (wave * 32 + t * 8) * 64 + lane * 8);
            async16(Bm + (size_t)(n0 + row) * K + k0 + crow * 8,
                    Bt + (wave * 32 + t * 8) * 64 + lane * 8);
        }
        __syncthreads();
#pragma unroll
        for (int ks = 0; ks < 2; ++ks) {
            bf16x8 af[4], bf[4];
#pragma unroll
            for (int mf = 0; mf < 4; ++mf) {
                const int ml = mhalf * 64 + mf * 16 + l15;
                const int c = (ks * 4 + quad) ^ (ml & 7);
                af[mf] = *(const bf16x8*)(At + ml * 64 + c * 8);
            }
#pragma unroll
            for (int nf = 0; nf < 4; ++nf) {
                const int nl = nhalf * 64 + nf * 16 + l15;
                const int c = (ks * 4 + quad) ^ (nl & 7);
                bf[nf] = *(const bf16x8*)(Bt + nl * 64 + c * 8);
            }
#pragma unroll
            for (int mf = 0; mf < 4; ++mf)
#pragma unroll
                for (int nf = 0; nf < 4; ++nf)
                    acc[mf][nf] = __builtin_amdgcn_mfma_f32_16x16x32_bf16(
                        af[mf], bf[nf], acc[mf][nf], 0, 0, 0);
        }
    }

    if (z == 2) {
#pragma unroll
        for (int mf = 0; mf < 4; ++mf)
#pragma unroll
            for (int nf = 0; nf < 4; ++nf) {
                const int row = m0 + mhalf * 64 + mf * 16 + quad * 4;
                const int col = n0 + nhalf * 64 + nf * 16 + l15;
                const int b_ = row >> 11, l_ = row & 2047;
                const int h_ = col >> 8, d_ = col & 255;
                us4 pk;
#pragma unroll
                for (int r = 0; r < 4; ++r) pk[r] = f2bf(acc[mf][nf][r]);
                *(us4*)(vt_out + (((size_t)(b_ * 8 + h_) * 256 + d_) * 2048 + l_)) = pk;
            }
    } else {
        ushort_t* Cout = z ? k_out : q_out;
        const float sc = z ? 1.0f : 0.0625f;   // fold 1/sqrt(256) into Q (exact)
#pragma unroll
        for (int mf = 0; mf < 4; ++mf)
#pragma unroll
            for (int nf = 0; nf < 4; ++nf)
#pragma unroll
                for (int r = 0; r < 4; ++r) {
                    const int row = m0 + mhalf * 64 + mf * 16 + quad * 4 + r;
                    const int col = n0 + nhalf * 64 + nf * 16 + l15;
                    Cout[(size_t)row * N + col] = f2bf(acc[mf][nf][r] * sc);
                }
    }
}

// ---------------------------------------------------------------------------
// Output GEMM, split-K: C_partial[s][M][N] = A[M][Ks] * B[N][Ks]^T.
// ---------------------------------------------------------------------------
__global__ __launch_bounds__(256, 2) void out_gemm_splitk_kernel(
    const ushort_t* __restrict__ A, const ushort_t* __restrict__ Bm,
    float* __restrict__ Pout, int M, int N, int K)
{
    __shared__ ushort_t At[128 * 64];
    __shared__ ushort_t Bt[128 * 64];

    const int tid  = threadIdx.x;
    const int wave = tid >> 6;
    const int lane = tid & 63;
    const int quad = lane >> 4;
    const int l15  = lane & 15;
    const int mhalf = wave >> 1;
    const int nhalf = wave & 1;
    const int m0 = blockIdx.x * 128;
    const int n0 = blockIdx.y * 128;
    const int ks0 = blockIdx.z * 512;

    f32x4 acc[4][4];
#pragma unroll
    for (int mf = 0; mf < 4; ++mf)
#pragma unroll
        for (int nf = 0; nf < 4; ++nf)
#pragma unroll
            for (int r = 0; r < 4; ++r) acc[mf][nf][r] = 0.f;

    const int crow = (lane & 7) ^ (lane >> 3);

    for (int k0 = ks0; k0 < ks0 + 512; k0 += 64) {
        __syncthreads();
#pragma unroll
        for (int t = 0; t < 4; ++t) {
            const int row = wave * 32 + t * 8 + (lane >> 3);
            async16(A + (size_t)(m0 + row) * K + k0 + crow * 8,
                    At + (wave * 32 + t * 8) * 64 + lane * 8);
            async16(Bm + (size_t)(n0 + row) * K + k0 + crow * 8,
                    Bt + (wave * 32 + t * 8) * 64 + lane * 8);
        }
        __syncthreads();
#pragma unroll
        for (int ks = 0; ks < 2; ++ks) {
            bf16x8 af[4], bf[4];
#pragma unroll
            for (int mf = 0; mf < 4; ++mf) {
                const int ml = mhalf * 64 + mf * 16 + l15;
                const int c = (ks * 4 + quad) ^ (ml & 7);
                af[mf] = *(const bf16x8*)(At + ml * 64 + c * 8);
            }
#pragma unroll
            for (int nf = 0; nf < 4; ++nf) {
                const int nl = nhalf * 64 + nf * 16 + l15;
                const int c = (ks * 4 + quad) ^ (nl & 7);
                bf[nf] = *(const bf16x8*)(Bt + nl * 64 + c * 8);
            }
#pragma unroll
            for (int mf = 0; mf < 4; ++mf)
#pragma unroll
                for (int nf = 0; nf < 4; ++nf)
                    acc[mf][nf] = __builtin_amdgcn_mfma_f32_16x16x32_bf16(
                        af[mf], bf[nf], acc[mf][nf], 0, 0, 0);
        }
    }

    float* Cp = Pout + (size_t)blockIdx.z * M * N;
#pragma unroll
    for (int mf = 0; mf < 4; ++mf)
#pragma unroll
        for (int nf = 0; nf < 4; ++nf)
#pragma unroll
            for (int r = 0; r < 4; ++r) {
                const int row = m0 + mhalf * 64 + mf * 16 + quad * 4 + r;
                const int col = n0 + nhalf * 64 + nf * 16 + l15;
                Cp[(size_t)row * N + col] = acc[mf][nf][r];
            }
}

// sum the 4 split-K partials -> d_out. 524288 float4 elements.
__global__ void reduce4_kernel(const float4* __restrict__ p, float4* __restrict__ out)
{
    const int i = blockIdx.x * 256 + threadIdx.x;
    float4 a = p[i];
    const float4 b = p[i + 524288];
    const float4 c = p[i + 1048576];
    const float4 d = p[i + 1572864];
    a.x += b.x + c.x + d.x;
    a.y += b.y + c.y + d.y;
    a.z += b.z + c.z + d.z;
    a.w += b.w + c.w + d.w;
    out[i] = a;
}

// ---------------------------------------------------------------------------
// Unsplit output GEMM (fallback if workspace can't hold partials).
// ---------------------------------------------------------------------------
__global__ __launch_bounds__(256, 2) void out_gemm_kernel(
    const ushort_t* __restrict__ A, const ushort_t* __restrict__ Bm,
    float* __restrict__ Cout, int M, int N, int K)
{
    __shared__ ushort_t At[128 * 64];
    __shared__ ushort_t Bt[128 * 64];

    const int tid  = threadIdx.x;
    const int wave = tid >> 6;
    const int lane = tid & 63;
    const int quad = lane >> 4;
    const int l15  = lane & 15;
    const int mhalf = wave >> 1;
    const int nhalf = wave & 1;
    const int m0 = blockIdx.x * 128;
    const int n0 = blockIdx.y * 128;

    f32x4 acc[4][4];
#pragma unroll
    for (int mf = 0; mf < 4; ++mf)
#pragma unroll
        for (int nf = 0; nf < 4; ++nf)
#pragma unroll
            for (int r = 0; r < 4; ++r) acc[mf][nf][r] = 0.f;

    const int crow = (lane & 7) ^ (lane >> 3);

    for (int k0 = 0; k0 < K; k0 += 64) {
        __syncthreads();
#pragma unroll
        for (int t = 0; t < 4; ++t) {
            const int row = wave * 32 + t * 8 + (lane >> 3);
            async16(A + (size_t)(m0 + row) * K + k0 + crow * 8,
                    At + (wave * 32 + t * 8) * 64 + lane * 8);
            async16(Bm + (size_t)(n0 + row) * K + k0 + crow * 8,
                    Bt + (wave * 32 + t * 8) * 64 + lane * 8);
        }
        __syncthreads();
#pragma unroll
        for (int ks = 0; ks < 2; ++ks) {
            bf16x8 af[4], bf[4];
#pragma unroll
            for (int mf = 0; mf < 4; ++mf) {
                const int ml = mhalf * 64 + mf * 16 + l15;
                const int c = (ks * 4 + quad) ^ (ml & 7);
                af[mf] = *(const bf16x8*)(At + ml * 64 + c * 8);
            }
#pragma unroll
            for (int nf = 0; nf < 4; ++nf) {
                const int nl = nhalf * 64 + nf * 16 + l15;
                const int c = (ks * 4 + quad) ^ (nl & 7);
                bf[nf] = *(const bf16x8*)(Bt + nl * 64 + c * 8);
            }
#pragma unroll
            for (int mf = 0; mf < 4; ++mf)
#pragma unroll
                for (int nf = 0; nf < 4; ++nf)
                    acc[mf][nf] = __builtin_amdgcn_mfma_f32_16x16x32_bf16(
                        af[mf], bf[nf], acc[mf][nf], 0, 0, 0);
        }
    }

#pragma unroll
    for (int mf = 0; mf < 4; ++mf)
#pragma unroll
        for (int nf = 0; nf < 4; ++nf)
#pragma unroll
            for (int r = 0; r < 4; ++r) {
                const int row = m0 + mhalf * 64 + mf * 16 + quad * 4 + r;
                const int col = n0 + nhalf * 64 + nf * 16 + l15;
                Cout[(size_t)row * N + col] = acc[mf][nf][r];
            }
}

// ---------------------------------------------------------------------------
// Pass 1 (128-row blocks): Z_i = sum_j exp(s_ij), s pre-scaled via Q.
// Grid 512 = 32 bh x 16 i-tiles of 128 rows, 512 threads (8 waves: 4 iq x 2
// jhalf). Each staged K tile serves 128 Q rows (2x arithmetic intensity vs
// 64-row blocks); LDS 33 KB -> 4 blocks/CU = 32 waves/CU.
// ---------------------------------------------------------------------------
__global__ __launch_bounds__(512, 4) void pass1_kernel(
    const ushort_t* __restrict__ q_ws, const ushort_t* __restrict__ k_ws,
    float* __restrict__ rz_ws)
{
    __shared__ ushort_t Kt[64 * 256];   // 32 KB, chunk-swizzled
    __shared__ float zred[2][128];

    const int tid  = threadIdx.x;
    const int wave = tid >> 6;          // 0..7
    const int lane = tid & 63;
    const int quad = lane >> 4;
    const int l15  = lane & 15;
    const int iq    = wave >> 1;        // 0..3 : 32-row group
    const int jhalf = wave & 1;

    const int g  = blockIdx.x;          // 512
    const int h  = g & 7;
    const int b  = (g >> 3) & 3;
    const int it = g >> 5;              // 0..15
    const int bh = b * 8 + h;
    const int i0 = it * 128;

    const size_t qkbase = (size_t)b * 2048 * 2048 + (size_t)h * 256;

    // Q fragments (B-operand layout: n=l15 -> row i, k=quad*8.. -> d)
    bf16x8 qf[2][8];
#pragma unroll
    for (int ng = 0; ng < 2; ++ng) {
        const int i_l = iq * 32 + ng * 16 + l15;
        const ushort_t* qr = q_ws + qkbase + (size_t)(i0 + i_l) * 2048;
#pragma unroll
        for (int ks = 0; ks < 8; ++ks)
            qf[ng][ks] = *(const bf16x8*)(qr + ks * 32 + quad * 8);
    }

    float z[2] = {0.f, 0.f};

    for (int jt = 0; jt < 32; ++jt) {
        __syncthreads();
        {
            const ushort_t* kb = k_ws + qkbase + (size_t)jt * 64 * 2048;
#pragma unroll
            for (int t = 0; t < 4; ++t) {
                const int row = wave * 8 + t * 2 + (lane >> 5);
                const int c = (lane & 31) ^ (row & 7);
                async16(kb + (size_t)row * 2048 + c * 8,
                        Kt + (wave * 8 + t * 2) * 256 + lane * 8);
            }
        }
        __syncthreads();

        f32x4 sacc[2][2];
#pragma unroll
        for (int a = 0; a < 2; ++a)
#pragma unroll
            for (int c = 0; c < 2; ++c)
#pragma unroll
                for (int r = 0; r < 4; ++r) sacc[a][c][r] = 0.f;

        __builtin_amdgcn_s_setprio(1);
#pragma unroll
        for (int ks = 0; ks < 8; ++ks) {
            bf16x8 af[2];
#pragma unroll
            for (int mg = 0; mg < 2; ++mg) {
                const int j_l = jhalf * 32 + mg * 16 + l15;
                const int c = (ks * 4 + quad) ^ (j_l & 7);
                af[mg] = *(const bf16x8*)(Kt + j_l * 256 + c * 8);
            }
#pragma unroll
            for (int mg = 0; mg < 2; ++mg)
#pragma unroll
                for (int ng = 0; ng < 2; ++ng)
                    sacc[mg][ng] = __builtin_amdgcn_mfma_f32_16x16x32_bf16(
                        af[mg], qf[ng][ks], sacc[mg][ng], 0, 0, 0);
        }
        __builtin_amdgcn_s_setprio(0);

#pragma unroll
        for (int ng = 0; ng < 2; ++ng)
#pragma unroll
            for (int mg = 0; mg < 2; ++mg)
#pragma unroll
                for (int r = 0; r < 4; ++r)
                    z[ng] += __expf(sacc[mg][ng][r]);
    }

    // reduce z across quads (same jhalf), then across jhalf via LDS
#pragma unroll
    for (int ng = 0; ng < 2; ++ng) {
        z[ng] += __shfl_xor(z[ng], 16);
        z[ng] += __shfl_xor(z[ng], 32);
    }
    __syncthreads();
    if (quad == 0) {
#pragma unroll
        for (int ng = 0; ng < 2; ++ng) {
            const int i_l = iq * 32 + ng * 16 + l15;
            zred[jhalf][i_l] = z[ng];
        }
    }
    __syncthreads();
    if (tid < 128)
        rz_ws[(size_t)bh * 2048 + i0 + tid] = 1.0f / (zred[0][tid] + zred[1][tid]);
}

// ---------------------------------------------------------------------------
// Pass 2 (128-row blocks): causal w = exp(exp(s)*rz); PV; divide by sum(w).
// Grid 512, 512 threads (8 waves). LDS 80 KB (Kt 32 + Vt 32 + Wt[128][64] 16)
// = exactly 2 blocks/CU (160 KiB) -> 16 waves/CU, and half the tile-stages
// of the 64-row version. Balanced it-pairing: blocks g and g+256 (same CU
// under round-robin) sum to a constant 34 j-tiles.
// ---------------------------------------------------------------------------
__global__ __launch_bounds__(512, 2) void pass2_kernel(
    const ushort_t* __restrict__ q_ws, const ushort_t* __restrict__ k_ws,
    const ushort_t* __restrict__ vt_ws, const float* __restrict__ rz_ws,
    ushort_t* __restrict__ attn_out)
{
    __shared__ ushort_t smem[40960];          // 80 KB
    ushort_t* Kt = smem;                      // [64][256] swizzled (32 KB)
    ushort_t* Vt = smem + 16384;              // [256][64] swizzled (32 KB)
    ushort_t* Wt = smem + 32768;              // [128][64] swizzled (16 KB)

    const int tid  = threadIdx.x;
    const int wave = tid >> 6;                // 0..7
    const int lane = tid & 63;
    const int quad = lane >> 4;
    const int l15  = lane & 15;
    const int iq    = wave >> 1;              // 0..3
    const int jhalf = wave & 1;

    const int g  = blockIdx.x;                // 512
    const int h  = g & 7;
    const int b  = (g >> 3) & 3;
    const int x  = g >> 5;                    // 0..15
    const int it = (x < 8) ? (2 * x) : (31 - 2 * x);  // pair sums = 15
    const int bh = b * 8 + h;
    const int i0 = it * 128;

    const size_t qkbase = (size_t)b * 2048 * 2048 + (size_t)h * 256;

    bf16x8 qf[2][8];
#pragma unroll
    for (int ng = 0; ng < 2; ++ng) {
        const int i_l = iq * 32 + ng * 16 + l15;
        const ushort_t* qr = q_ws + qkbase + (size_t)(i0 + i_l) * 2048;
#pragma unroll
        for (int ks = 0; ks < 8; ++ks)
            qf[ng][ks] = *(const bf16x8*)(qr + ks * 32 + quad * 8);
    }

    float rzrow[2];
#pragma unroll
    for (int ng = 0; ng < 2; ++ng) {
        const int i_l = iq * 32 + ng * 16 + l15;
        rzrow[ng] = rz_ws[(size_t)bh * 2048 + i0 + i_l];
    }

    f32x4 oacc[2][8];
#pragma unroll
    for (int mg = 0; mg < 2; ++mg)
#pragma unroll
        for (int nf = 0; nf < 8; ++nf)
#pragma unroll
            for (int r = 0; r < 4; ++r) oacc[mg][nf][r] = 0.f;
    float den[2] = {0.f, 0.f};

    const int jmax = 2 * it + 1;
    for (int jt = 0; jt <= jmax; ++jt) {
        const int j0 = jt * 64;
        const int jzone = jt - 2 * it;        // >=0: masking zone
        __syncthreads();
        {
            const ushort_t* kb = k_ws + qkbase + (size_t)j0 * 2048;
#pragma unroll
            for (int t = 0; t < 4; ++t) {
                const int row = wave * 8 + t * 2 + (lane >> 5);
                const int c = (lane & 31) ^ (row & 7);
                async16(kb + (size_t)row * 2048 + c * 8,
                        Kt + (wave * 8 + t * 2) * 256 + lane * 8);
            }
            const ushort_t* vb = vt_ws + (size_t)bh * 256 * 2048 + j0;
#pragma unroll
            for (int t = 0; t < 4; ++t) {
                const int row = wave * 32 + t * 8 + (lane >> 3);
                const int c = (lane & 7) ^ (row & 7);
                async16(vb + (size_t)row * 2048 + c * 8,
                        Vt + (wave * 32 + t * 8) * 64 + lane * 8);
            }
        }
        __syncthreads();

        f32x4 sacc[2][2];
#pragma unroll
        for (int a = 0; a < 2; ++a)
#pragma unroll
            for (int c = 0; c < 2; ++c)
#pragma unroll
                for (int r = 0; r < 4; ++r) sacc[a][c][r] = 0.f;

#pragma unroll
        for (int ks = 0; ks < 8; ++ks) {
            bf16x8 af[2];
#pragma unroll
            for (int mg = 0; mg < 2; ++mg) {
                const int j_l = jhalf * 32 + mg * 16 + l15;
                const int c = (ks * 4 + quad) ^ (j_l & 7);
                af[mg] = *(const bf16x8*)(Kt + j_l * 256 + c * 8);
            }
#pragma unroll
            for (int mg = 0; mg < 2; ++mg)
#pragma unroll
                for (int ng = 0; ng < 2; ++ng)
                    sacc[mg][ng] = __builtin_amdgcn_mfma_f32_16x16x32_bf16(
                        af[mg], qf[ng][ks], sacc[mg][ng], 0, 0, 0);
        }

        // w = exp(exp(s)*rz), causal-masked; pack -> Wt[i][j] (swizzled)
#pragma unroll
        for (int mg = 0; mg < 2; ++mg) {
#pragma unroll
            for (int ng = 0; ng < 2; ++ng) {
                const int i_l = iq * 32 + ng * 16 + l15;
                const int jb = jhalf * 32 + mg * 16 + quad * 4;
                us4 wp;
#pragma unroll
                for (int r = 0; r < 4; ++r) {
                    const float p = __expf(sacc[mg][ng][r]) * rzrow[ng];
                    float w = __expf(p);
                    if (jzone >= 0 && (jzone * 64 + jb + r > i_l)) w = 0.f;
                    den[ng] += w;
                    wp[r] = f2bf(w);
                }
                const int c = (jb >> 3) ^ (i_l & 7);
                *(us4*)(Wt + i_l * 64 + c * 8 + (jb & 7)) = wp;
            }
        }
        __syncthreads();

        // PV: oacc[32 i][128 d] += Wt x Vt (per wave: iq rows, jhalf d-half)
#pragma unroll
        for (int ks = 0; ks < 2; ++ks) {
            bf16x8 aw[2];
#pragma unroll
            for (int mg = 0; mg < 2; ++mg) {
                const int i_l = iq * 32 + mg * 16 + l15;
                const int c = (ks * 4 + quad) ^ (i_l & 7);
                aw[mg] = *(const bf16x8*)(Wt + i_l * 64 + c * 8);
            }
#pragma unroll
            for (int nf = 0; nf < 8; ++nf) {
                const int d = jhalf * 128 + nf * 16 + l15;
                const int c = (ks * 4 + quad) ^ (d & 7);
                const bf16x8 bv = *(const bf16x8*)(Vt + d * 64 + c * 8);
                oacc[0][nf] = __builtin_amdgcn_mfma_f32_16x16x32_bf16(aw[0], bv, oacc[0][nf], 0, 0, 0);
                oacc[1][nf] = __builtin_amdgcn_mfma_f32_16x16x32_bf16(aw[1], bv, oacc[1][nf], 0, 0, 0);
            }
        }
    }

    // epilogue: merge den across waves (8 partials/row), scale rows, store
    __syncthreads();
    {
        float* dbuf = (float*)Kt; // [8][128]
#pragma unroll
        for (int ng = 0; ng < 2; ++ng) {
            const int i_l = iq * 32 + ng * 16 + l15;
            dbuf[(jhalf * 4 + quad) * 128 + i_l] = den[ng];
        }
    }
    __syncthreads();
    if (tid < 128) {
        const float* dbuf = (const float*)Kt;
        float s = 0.f;
#pragma unroll
        for (int p = 0; p < 8; ++p) s += dbuf[p * 128 + tid];
        ((float*)Kt)[1024 + tid] = 1.0f / s;
    }
    __syncthreads();
    {
        const float* rden = (const float*)Kt + 1024;
#pragma unroll
        for (int mg = 0; mg < 2; ++mg) {
#pragma unroll
            for (int r = 0; r < 4; ++r) {
                const int i_l = iq * 32 + mg * 16 + quad * 4 + r;
                const float rd = rden[i_l];
                ushort_t* orow = attn_out + qkbase + (size_t)(i0 + i_l) * 2048;
#pragma unroll
                for (int nf = 0; nf < 8; ++nf) {
                    const int d = jhalf * 128 + nf * 16 + l15;
                    orow[d] = f2bf(oacc[mg][nf][r] * rd);
                }
            }
        }
    }
}

// ---------------------------------------------------------------------------
extern "C" void kernel_launch(void* const* d_in, const int* in_sizes, int n_in,
                              void* d_out, int out_size, void* d_ws, size_t ws_size,
                              hipStream_t stream) {
    const float* x  = (const float*)d_in[0];
    const float* Wq = (const float*)d_in[1];
    const float* Wk = (const float*)d_in[2];
    const float* Wv = (const float*)d_in[3];
    const float* Wo = (const float*)d_in[4];

    char* ws = (char*)d_ws;
    ushort_t* xb    = (ushort_t*)(ws);
    ushort_t* wqb   = (ushort_t*)(ws + 4194304);
    ushort_t* wkb   = (ushort_t*)(ws + 5242880);
    ushort_t* wvb   = (ushort_t*)(ws + 6291456);
    ushort_t* wob   = (ushort_t*)(ws + 7340032);
    ushort_t* q_ws  = (ushort_t*)(ws + 8388608);
    ushort_t* k_ws  = (ushort_t*)(ws + 41943040);
    ushort_t* vt_ws = (ushort_t*)(ws + 75497472);
    ushort_t* ao_ws = (ushort_t*)(ws + 109051904);
    float*    rz_ws = (float*)   (ws + 142606336);   // 32*2048 floats, ends 142868480

    // split-K partials: 4 x 8192 x 256 f32 = 32 MB
    const size_t PG_OFF = 142868480ull;
    const size_t PG_END = PG_OFF + 33554432ull;      // 176,422,912
    const bool use_splitk = ws_size >= PG_END;
    float* pg_ws = (float*)(ws + PG_OFF);

    convert_kernel<<<4096, 256, 0, stream>>>(x, Wq, Wk, Wv, Wo, xb, wqb, wkb, wvb, wob);

    qkv_gemm_kernel<<<dim3(64, 16, 3), 256, 0, stream>>>(
        xb, wqb, wkb, wvb, q_ws, k_ws, vt_ws);

    pass1_kernel<<<512, 512, 0, stream>>>(q_ws, k_ws, rz_ws);
    pass2_kernel<<<512, 512, 0, stream>>>(q_ws, k_ws, vt_ws, rz_ws, ao_ws);

    if (use_splitk) {
        out_gemm_splitk_kernel<<<dim3(64, 2, 4), 256, 0, stream>>>(
            ao_ws, wob, pg_ws, 8192, 256, 2048);
        reduce4_kernel<<<2048, 256, 0, stream>>>(
            (const float4*)pg_ws, (float4*)d_out);
    } else {
        out_gemm_kernel<<<dim3(64, 2), 256, 0, stream>>>(
            ao_ws, wob, (float*)d_out, 8192, 256, 2048);
    }
}